// Round 7
// baseline (926.974 us; speedup 1.0000x reference)
//
#include <hip/hip_runtime.h>

// SlayerLoihiMLP: bit-exact f32 replication of the numpy reference (verified
// rounds 5/6, absmax 0.0). Sparse + prepacked masks + literal-tap conv.
// Exactness invariants (unchanged):
//  - GEMM: per-output ordered ascending-i f32 sum; skipping x==0 terms is
//    bit-exact (acc can never be -0.0 under RNE; +/-0 adds are identity).
//  - conv: f32 mul then add (contract OFF), taps tau-descending per output,
//    taps = (64*SRM_KERNEL)/64 exact; *64.0f (exact) then trunc-to-int32.
//  - neuron dynamics: bit-exact int32 with jnp wrap semantics.

constexpr int kT     = 512;
constexpr int kCIN   = 512;
constexpr int kHID   = 1024;
constexpr int kCOUT  = 256;
constexpr int kB     = 32;
constexpr int kTHETA = 5120;   // 80 << 6
constexpr int kOT    = 8;      // output channels per block
constexpr int kSBP   = 516;    // sbuf row pitch (bytes)
constexpr int kCURP  = 520;    // cur row pitch (ints)

// ---- SRM kernel taps at compile time: kerf[tau] = (64*SRM_KERNEL[tau])/64 ----
struct Ker { float v[96]; int n; };
constexpr Ker mk_ker() {
    Ker K{}; int u = 64, v = 64; K.v[0] = 1.0f; int i = 1;
    while (v > 0 && i < 96) {
        u = (u * 3072) >> 12;
        v = ((v * 3968) >> 12) + u;
        K.v[i++] = (float)v / 64.0f;   // exact (v <= 194)
    }
    K.n = i; return K;
}
constexpr Ker KER = mk_ker();
static_assert(KER.n == 88, "SRM kernel length must be 88");

__device__ __forceinline__ int decay_i(int x, int mult) {
    unsigned ax = (x >= 0) ? (unsigned)x : (0u - (unsigned)x);
    unsigned p  = ax * (unsigned)mult;   // int32 wrap like jnp
    int sh = ((int)p) >> 12;             // arithmetic shift like jnp int32 >>
    return (x >= 0) ? sh : (int)(0u - (unsigned)sh);
}

// =============== k0: pack X into bit masks XPW[b][w=i/32][t] =================
__global__ __launch_bounds__(256) void k0_pack(const float* __restrict__ X,
                                               unsigned* __restrict__ XPW) {
    const int tid = blockIdx.x * 256 + threadIdx.x;   // [b][w][t] flat
    const int b = tid >> 13, rem = tid & 8191, w = rem >> 9, t = rem & 511;
    const float* xp = X + ((size_t)(b * kCIN + w * 32)) * kT + t;
    unsigned m = 0;
#pragma unroll
    for (int k = 0; k < 32; ++k)
        m |= (xp[(size_t)k * kT] != 0.0f ? 1u : 0u) << k;
    XPW[tid] = m;
}

// ---- shared conv helpers (2 cols/thread, row-pair float4 layout) ----
#define LOADF4(RP) \
    const float4 f0 = hbq[(RP)], f1 = hbq[256 + (RP)], \
                 f2 = hbq[512 + (RP)], f3 = hbq[768 + (RP)];
#define ACC_EVEN(C, KV) \
    C[0]=C[0]+(KV)*f0.x; C[1]=C[1]+(KV)*f0.y; C[2]=C[2]+(KV)*f1.x; C[3]=C[3]+(KV)*f1.y; \
    C[4]=C[4]+(KV)*f2.x; C[5]=C[5]+(KV)*f2.y; C[6]=C[6]+(KV)*f3.x; C[7]=C[7]+(KV)*f3.y;
#define ACC_ODD(C, KV) \
    C[0]=C[0]+(KV)*f0.z; C[1]=C[1]+(KV)*f0.w; C[2]=C[2]+(KV)*f1.z; C[3]=C[3]+(KV)*f1.w; \
    C[4]=C[4]+(KV)*f2.z; C[5]=C[5]+(KV)*f2.w; C[6]=C[6]+(KV)*f3.z; C[7]=C[7]+(KV)*f3.w;
#define ACC_TAIL(C, KV) \
    C[0]=C[0]+(KV)*(od?f0.z:f0.x); C[1]=C[1]+(KV)*(od?f0.w:f0.y); \
    C[2]=C[2]+(KV)*(od?f1.z:f1.x); C[3]=C[3]+(KV)*(od?f1.w:f1.y); \
    C[4]=C[4]+(KV)*(od?f2.z:f2.x); C[5]=C[5]+(KV)*(od?f2.w:f2.y); \
    C[6]=C[6]+(KV)*(od?f3.z:f3.x); C[7]=C[7]+(KV)*(od?f3.w:f3.y);

// sparse gather of one 32-bit mask word into 8 named accumulators
#define GWORD(MW, BASE) { unsigned m_ = (MW); while (m_) { \
    const int bi_ = __ffs(m_) - 1; m_ &= m_ - 1; const int ii_ = (BASE) + bi_; \
    const float4 lo = *reinterpret_cast<const float4*>(&wlo[ii_ * 4]); \
    const float4 hi = *reinterpret_cast<const float4*>(&whi[ii_ * 4]); \
    a0=a0+lo.x; a1=a1+lo.y; a2=a2+lo.z; a3=a3+lo.w; \
    a4=a4+hi.x; a5=a5+hi.y; a6=a6+hi.z; a7=a7+hi.w; } }

// conv phase shared by both kernels (expects hbq, c0[8], c1[8], q in scope)
#define CONV_BODY() \
    if (q >= 44) { \
        { LOADF4(q - 44) ACC_ODD(c0, KER.v[87]) } \
        _Pragma("unroll") \
        for (int s = 43; s >= 1; --s) { \
            LOADF4(q - s) \
            ACC_EVEN(c1, KER.v[2*s+1]) ACC_EVEN(c0, KER.v[2*s]) \
            ACC_ODD (c1, KER.v[2*s])   ACC_ODD (c0, KER.v[2*s-1]) \
        } \
        { LOADF4(q) ACC_EVEN(c1, KER.v[1]) ACC_EVEN(c0, KER.v[0]) ACC_ODD(c1, KER.v[0]) } \
    } else { \
        const int t0c = 2*q, t1c = 2*q + 1; \
        for (int tau = t0c; tau >= 0; --tau) { \
            const int r = t0c - tau, rp = r >> 1; const bool od = (r & 1) != 0; \
            LOADF4(rp) const float kv = KER.v[tau]; ACC_TAIL(c0, kv) \
        } \
        for (int tau = t1c; tau >= 0; --tau) { \
            const int r = t1c - tau, rp = r >> 1; const bool od = (r & 1) != 0; \
            LOADF4(rp) const float kv = KER.v[tau]; ACC_TAIL(c1, kv) \
        } \
    }

// ============ k1: sparse GEMM (masks) + conv + int32 scan, fused =============
__global__ __launch_bounds__(512) void k1_fused(const unsigned* __restrict__ XPW,
                                                const float* __restrict__ W,
                                                unsigned char* __restrict__ SPT) {
#pragma clang fp contract(off)
    __shared__ float wlo[kCIN * 4];                  // W[o..o+3][i] as [i][4]
    __shared__ float whi[kCIN * 4];
    __shared__ __align__(16) unsigned char hc[16640]; // hbq f4[1024] / cur int[8][520]
    __shared__ unsigned char sbuf[kOT * kSBP];

    float4* hbq = reinterpret_cast<float4*>(hc);
    float2* hb2 = reinterpret_cast<float2*>(hc);
    int*    cur = reinterpret_cast<int*>(hc);

    const int t     = threadIdx.x;
    const int b     = blockIdx.x >> 7;               // 128 blocks per batch
    const int oblk  = blockIdx.x & 127;
    const int obase = oblk * kOT;

    for (int idx = t; idx < kOT * kCIN; idx += 512) {
        const int j = idx >> 9, i = idx & 511;
        const float w = W[(size_t)(obase + j) * kCIN + i];
        if (j < 4) wlo[i * 4 + j] = w; else whi[i * 4 + (j - 4)] = w;
    }
    __syncthreads();

    // ---- sparse GEMM: ordered ascending-i adds of W columns where x==1 ----
    const unsigned* xw = XPW + ((size_t)b * 16) * kT + t;
    float a0=0,a1=0,a2=0,a3=0,a4=0,a5=0,a6=0,a7=0;
    {
        const unsigned m0=xw[0],m1=xw[512],m2=xw[1024],m3=xw[1536],
                       m4=xw[2048],m5=xw[2560],m6=xw[3072],m7=xw[3584],
                       m8=xw[4096],m9=xw[4608],mA=xw[5120],mB=xw[5632],
                       mC=xw[6144],mD=xw[6656],mE=xw[7168],mF=xw[7680];
        GWORD(m0,0)   GWORD(m1,32)  GWORD(m2,64)  GWORD(m3,96)
        GWORD(m4,128) GWORD(m5,160) GWORD(m6,192) GWORD(m7,224)
        GWORD(m8,256) GWORD(m9,288) GWORD(mA,320) GWORD(mB,352)
        GWORD(mC,384) GWORD(mD,416) GWORD(mE,448) GWORD(mF,480)
    }

    // ---- stage h into row-pair float4 layout ----
    {
        const int rp = t >> 1, od = t & 1;
        hb2[(((0*256 + rp) << 1) | od)] = make_float2(a0, a1);
        hb2[(((1*256 + rp) << 1) | od)] = make_float2(a2, a3);
        hb2[(((2*256 + rp) << 1) | od)] = make_float2(a4, a5);
        hb2[(((3*256 + rp) << 1) | od)] = make_float2(a6, a7);
    }
    __syncthreads();

    // ---- conv: 2 cols per thread (cols 2q, 2q+1), taps tau-descending ----
    const int q = t;
    float c0[8] = {0,0,0,0,0,0,0,0}, c1[8] = {0,0,0,0,0,0,0,0};
    if (t < 256) { CONV_BODY() }
    __syncthreads();                                 // all hbq reads complete

    if (t < 256) {
        int2* cur2 = reinterpret_cast<int2*>(hc);
#pragma unroll
        for (int ch = 0; ch < 8; ++ch)
            cur2[ch * 260 + q] = make_int2((int)(c0[ch] * 64.0f),
                                           (int)(c1[ch] * 64.0f));
    }
    __syncthreads();

    // ---- serial int32 Loihi dynamics (lanes 0..7), PRE-DELAYED spikes ----
    if (t < kOT) {
        const int* cr = cur + t * kCURP;
        int u = 0, v = 0;
        sbuf[t * kSBP + 0] = 0;                      // delay_shift
        for (int s = 0; s < kT; ++s) {
            const int un = (int)((unsigned)decay_i(u, 3072) + (unsigned)cr[s]);
            int vn = (int)((unsigned)decay_i(v, 3968) + (unsigned)un);
            const int sp = (vn >= kTHETA) ? 1 : 0;
            if (sp) vn = 0;
            u = un; v = vn;
            if (s + 1 < kT) sbuf[t * kSBP + s + 1] = (unsigned char)sp;
        }
    }
    __syncthreads();

    // ---- pack 8 channel bits -> byte column SPT[b][oblk][t] ----
    unsigned byte = 0;
#pragma unroll
    for (int j = 0; j < kOT; ++j)
        byte |= (unsigned)sbuf[j * kSBP + t] << j;
    SPT[((size_t)b * 128 + oblk) * kT + t] = (unsigned char)byte;
}

// ============ k2: sparse GEMM over spike bytes + conv + scan + out ===========
__global__ __launch_bounds__(512) void k2_fused(const unsigned char* __restrict__ SPT,
                                                const float* __restrict__ W,
                                                float* __restrict__ O) {
#pragma clang fp contract(off)
    __shared__ float wlo[kHID * 4];                  // 16 KB
    __shared__ float whi[kHID * 4];                  // 16 KB
    __shared__ __align__(16) unsigned char hc[16640];
    __shared__ unsigned char sbuf[kOT * kSBP];

    float4* hbq = reinterpret_cast<float4*>(hc);
    float2* hb2 = reinterpret_cast<float2*>(hc);
    int*    cur = reinterpret_cast<int*>(hc);

    const int t     = threadIdx.x;
    const int b     = blockIdx.x >> 5;               // 32 blocks per batch
    const int obase = (blockIdx.x & 31) * kOT;

    for (int idx = t; idx < kOT * kHID; idx += 512) {
        const int j = idx >> 10, i = idx & 1023;
        const float w = W[(size_t)(obase + j) * kHID + i];
        if (j < 4) wlo[i * 4 + j] = w; else whi[i * 4 + (j - 4)] = w;
    }
    __syncthreads();

    // ---- assemble 32 mask words from 128 strided spike bytes ----
    const unsigned char* sp = SPT + (size_t)b * (128 * kT) + t;
    float a0=0,a1=0,a2=0,a3=0,a4=0,a5=0,a6=0,a7=0;
#define BW_(CB) ((unsigned)sp[(size_t)(CB) * kT])
#define MKW_(Wd) (BW_(4*(Wd)) | (BW_(4*(Wd)+1) << 8) | (BW_(4*(Wd)+2) << 16) | (BW_(4*(Wd)+3) << 24))
    {
        const unsigned w0=MKW_(0), w1=MKW_(1), w2=MKW_(2), w3=MKW_(3),
                       w4=MKW_(4), w5=MKW_(5), w6=MKW_(6), w7=MKW_(7),
                       w8=MKW_(8), w9=MKW_(9), wA=MKW_(10), wB=MKW_(11),
                       wC=MKW_(12), wD=MKW_(13), wE=MKW_(14), wF=MKW_(15);
        const unsigned g0=MKW_(16), g1=MKW_(17), g2=MKW_(18), g3=MKW_(19),
                       g4=MKW_(20), g5=MKW_(21), g6=MKW_(22), g7=MKW_(23),
                       g8=MKW_(24), g9=MKW_(25), gA=MKW_(26), gB=MKW_(27),
                       gC=MKW_(28), gD=MKW_(29), gE=MKW_(30), gF=MKW_(31);
        GWORD(w0,0)   GWORD(w1,32)  GWORD(w2,64)  GWORD(w3,96)
        GWORD(w4,128) GWORD(w5,160) GWORD(w6,192) GWORD(w7,224)
        GWORD(w8,256) GWORD(w9,288) GWORD(wA,320) GWORD(wB,352)
        GWORD(wC,384) GWORD(wD,416) GWORD(wE,448) GWORD(wF,480)
        GWORD(g0,512) GWORD(g1,544) GWORD(g2,576) GWORD(g3,608)
        GWORD(g4,640) GWORD(g5,672) GWORD(g6,704) GWORD(g7,736)
        GWORD(g8,768) GWORD(g9,800) GWORD(gA,832) GWORD(gB,864)
        GWORD(gC,896) GWORD(gD,928) GWORD(gE,960) GWORD(gF,992)
    }

    {
        const int rp = t >> 1, od = t & 1;
        hb2[(((0*256 + rp) << 1) | od)] = make_float2(a0, a1);
        hb2[(((1*256 + rp) << 1) | od)] = make_float2(a2, a3);
        hb2[(((2*256 + rp) << 1) | od)] = make_float2(a4, a5);
        hb2[(((3*256 + rp) << 1) | od)] = make_float2(a6, a7);
    }
    __syncthreads();

    const int q = t;
    float c0[8] = {0,0,0,0,0,0,0,0}, c1[8] = {0,0,0,0,0,0,0,0};
    if (t < 256) { CONV_BODY() }
    __syncthreads();

    if (t < 256) {
        int2* cur2 = reinterpret_cast<int2*>(hc);
#pragma unroll
        for (int ch = 0; ch < 8; ++ch)
            cur2[ch * 260 + q] = make_int2((int)(c0[ch] * 64.0f),
                                           (int)(c1[ch] * 64.0f));
    }
    __syncthreads();

    if (t < kOT) {
        const int* cr = cur + t * kCURP;
        int u = 0, v = 0;
        sbuf[t * kSBP + 0] = 0;                      // delay_shift on output
        for (int s = 0; s < kT; ++s) {
            const int un = (int)((unsigned)decay_i(u, 3072) + (unsigned)cr[s]);
            int vn = (int)((unsigned)decay_i(v, 3968) + (unsigned)un);
            const int sp2 = (vn >= kTHETA) ? 1 : 0;
            if (sp2) vn = 0;
            u = un; v = vn;
            if (s + 1 < kT) sbuf[t * kSBP + s + 1] = (unsigned char)sp2;
        }
    }
    __syncthreads();

    for (int idx = t; idx < kOT * kT; idx += 512) {
        const int j = idx >> 9, tt = idx & 511;
        O[((size_t)(b * kCOUT + obase + j)) * kT + tt] = (float)sbuf[j * kSBP + tt];
    }
}

__global__ void k_mark(float* __restrict__ out0, float v) {
    if (threadIdx.x == 0 && blockIdx.x == 0) out0[0] = v;
}

extern "C" void kernel_launch(void* const* d_in, const int* in_sizes, int n_in,
                              void* d_out, int out_size, void* d_ws, size_t ws_size,
                              hipStream_t stream) {
    const float* X  = (const float*)d_in[0];   // (32,512,1,1,512) spikes {0,1}
    const float* W1 = (const float*)d_in[1];   // (1024,512)
    const float* W2 = (const float*)d_in[2];   // (256,1024)
    float* OUT = (float*)d_out;                // (32,256,1,1,512)

    const size_t xpw_bytes = (size_t)kB * 16 * kT * 4;      // 1 MiB
    const size_t spt_bytes = (size_t)kB * 128 * kT;         // 2 MiB
    const size_t need = xpw_bytes + spt_bytes;

    if (n_in != 3 || in_sizes[0] != kB * kCIN * kT || in_sizes[1] != kHID * kCIN ||
        in_sizes[2] != kCOUT * kHID || out_size != kB * kCOUT * kT) {
        hipLaunchKernelGGL(k_mark, dim3(1), dim3(64), 0, stream, OUT, 7000001.0f);
        return;
    }
    if (ws_size < need || d_ws == nullptr) {
        const float v = (float)(8000000u + (unsigned)((ws_size >> 10) % 900000));
        hipLaunchKernelGGL(k_mark, dim3(1), dim3(64), 0, stream, OUT, v);
        return;
    }

    unsigned*      xpw = (unsigned*)d_ws;
    unsigned char* spt = (unsigned char*)d_ws + xpw_bytes;

    hipLaunchKernelGGL(k0_pack, dim3(kB * 16 * kT / 256), dim3(256), 0, stream,
                       X, xpw);
    hipLaunchKernelGGL(k1_fused, dim3(kB * (kHID / kOT)), dim3(512), 0, stream,
                       xpw, W1, spt);
    hipLaunchKernelGGL(k2_fused, dim3(kB * (kCOUT / kOT)), dim3(512), 0, stream,
                       spt, W2, OUT);
}

// Round 8
// 694.003 us; speedup vs baseline: 1.3357x; 1.3357x over previous
//
#include <hip/hip_runtime.h>

// SlayerLoihiMLP: bit-exact f32 replication of the numpy reference (verified
// rounds 5/6, absmax 0.0). Round 8 = round-6 structure (proven) + k0 prepack
// (round-7's one win) + packed-float2 arithmetic (order-preserving).
// Exactness invariants:
//  - GEMM: per-output ordered ascending-i f32 sum; skipping x==0 terms is
//    bit-exact (RNE running sums never produce -0.0; +0.0 adds are identity).
//  - conv: f32 mul then add (contract OFF file-wide), taps tau-descending,
//    taps = (64*SRM_KERNEL)/64 exact; *64.0f (exact) then trunc-to-int32.
//  - neuron dynamics: bit-exact int32 with jnp wrap semantics.
//  - float2 packing pairs INDEPENDENT channel accumulators: per-channel
//    op sequence identical to scalar.

#pragma clang fp contract(off)

constexpr int kT     = 512;
constexpr int kCIN   = 512;
constexpr int kHID   = 1024;
constexpr int kCOUT  = 256;
constexpr int kB     = 32;
constexpr int kKMAX  = 96;     // actual SRM kernel length = 88
constexpr int kTHETA = 5120;   // 80 << 6
constexpr int kOT    = 8;      // output channels per block
constexpr int kHBP   = 12;     // h pitch (floats): 48B; 8 consecutive lanes'
                               // 2xb128 reads cover all 32 banks disjointly
constexpr int kSBP   = 516;    // sbuf row pitch (bytes)
constexpr int kCURP  = 520;    // cur row pitch (ints)

__device__ __forceinline__ float2 pkmul(const float2 a, const float b) {
    return make_float2(a.x * b, a.y * b);
}
__device__ __forceinline__ float2 pkadd(const float2 a, const float2 b) {
    return make_float2(a.x + b.x, a.y + b.y);
}

__device__ __forceinline__ int decay_i(int x, int mult) {
    unsigned ax = (x >= 0) ? (unsigned)x : (0u - (unsigned)x);
    unsigned p  = ax * (unsigned)mult;   // int32 wrap like jnp
    int sh = ((int)p) >> 12;             // arithmetic shift like jnp int32 >>
    return (x >= 0) ? sh : (int)(0u - (unsigned)sh);
}

// taps kerf[tau] = (64*SRM_KERNEL[tau])/64, exact in f32 (values <= 194)
__device__ __forceinline__ int build_ker_f(float* kerf) {
    int u = 64, v = 64;
    kerf[0] = 1.0f;
    int i = 1;
    while (v > 0 && i < kKMAX) {
        u = (u * 3072) >> 12;
        v = ((v * 3968) >> 12) + u;
        kerf[i++] = (float)v * 0.015625f;
    }
    return i;  // 88, includes trailing zero tap (harmless)
}

// sparse gather of one 32-bit mask word into 4 float2 accumulators
#define GWORD(MW, BASE) { unsigned m_ = (MW); while (m_) { \
    const int bi_ = __ffs(m_) - 1; m_ &= m_ - 1; const int ii_ = (BASE) + bi_; \
    const float4 lo = *reinterpret_cast<const float4*>(&wlo[ii_ * 4]); \
    const float4 hi = *reinterpret_cast<const float4*>(&whi[ii_ * 4]); \
    const float2* l2_ = reinterpret_cast<const float2*>(&lo); \
    const float2* h2_ = reinterpret_cast<const float2*>(&hi); \
    A01 = pkadd(A01, l2_[0]); A23 = pkadd(A23, l2_[1]); \
    A45 = pkadd(A45, h2_[0]); A67 = pkadd(A67, h2_[1]); } }

// =============== k0: pack X into bit masks XPW[b][w=i/32][t] =================
__global__ __launch_bounds__(256) void k0_pack(const float* __restrict__ X,
                                               unsigned* __restrict__ XPW) {
    const int tid = blockIdx.x * 256 + threadIdx.x;   // [b][w][t] flat
    const int b = tid >> 13, rem = tid & 8191, w = rem >> 9, t = rem & 511;
    const float* xp = X + ((size_t)(b * kCIN + w * 32)) * kT + t;
    unsigned m = 0;
#pragma unroll
    for (int k = 0; k < 32; ++k)
        m |= (xp[(size_t)k * kT] != 0.0f ? 1u : 0u) << k;
    XPW[tid] = m;
}

// ============ k1: sparse GEMM (masks) + conv + int32 scan, fused =============
__global__ __launch_bounds__(512) void k1_fused(const unsigned* __restrict__ XPW,
                                                const float* __restrict__ W,
                                                unsigned char* __restrict__ SPT) {
    __shared__ float wlo[kCIN * 4];                   // W[o..o+3][i] as [i][4]
    __shared__ float whi[kCIN * 4];
    __shared__ __align__(16) float hbf[kT * kHBP];    // 24 KB, aliased as cur
    __shared__ unsigned char sbuf[kOT * kSBP];
    __shared__ float kerf[kKMAX];
    __shared__ int   kn_s;

    int* cur = reinterpret_cast<int*>(hbf);

    const int t     = threadIdx.x;                    // one thread per timestep
    const int b     = blockIdx.x >> 7;                // 128 blocks per batch
    const int oblk  = blockIdx.x & 127;
    const int obase = oblk * kOT;

    if (t == 0) kn_s = build_ker_f(kerf);
    for (int idx = t; idx < kOT * kCIN; idx += 512) {
        const int j = idx >> 9, i = idx & 511;
        const float w = W[(size_t)(obase + j) * kCIN + i];
        if (j < 4) wlo[i * 4 + j] = w; else whi[i * 4 + (j - 4)] = w;
    }
    __syncthreads();

    // ---- sparse GEMM: ordered ascending-i adds of W columns where x==1 ----
    const unsigned* xw = XPW + ((size_t)b * 16) * kT + t;
    float2 A01 = make_float2(0.f, 0.f), A23 = A01, A45 = A01, A67 = A01;
    {
        const unsigned m0=xw[0],    m1=xw[512],  m2=xw[1024], m3=xw[1536],
                       m4=xw[2048], m5=xw[2560], m6=xw[3072], m7=xw[3584],
                       m8=xw[4096], m9=xw[4608], mA=xw[5120], mB=xw[5632],
                       mC=xw[6144], mD=xw[6656], mE=xw[7168], mF=xw[7680];
        GWORD(m0,0)   GWORD(m1,32)  GWORD(m2,64)  GWORD(m3,96)
        GWORD(m4,128) GWORD(m5,160) GWORD(m6,192) GWORD(m7,224)
        GWORD(m8,256) GWORD(m9,288) GWORD(mA,320) GWORD(mB,352)
        GWORD(mC,384) GWORD(mD,416) GWORD(mE,448) GWORD(mF,480)
    }

    // ---- stage h (pitch-12 layout; b64 writes, 16B-aligned base) ----
    *reinterpret_cast<float2*>(&hbf[t * kHBP + 0]) = A01;
    *reinterpret_cast<float2*>(&hbf[t * kHBP + 2]) = A23;
    *reinterpret_cast<float2*>(&hbf[t * kHBP + 4]) = A45;
    *reinterpret_cast<float2*>(&hbf[t * kHBP + 6]) = A67;
    __syncthreads();

    // ---- conv: 1 col/thread, taps tau-descending, packed-f32 mul+add ----
    float2 c01 = make_float2(0.f, 0.f), c23 = c01, c45 = c01, c67 = c01;
    {
        const int kmax = min(t + 1, kn_s);
        for (int tau = kmax - 1; tau >= 0; --tau) {
            const float kv = kerf[tau];
            const float4 lo = *reinterpret_cast<const float4*>(&hbf[(t - tau) * kHBP]);
            const float4 hi = *reinterpret_cast<const float4*>(&hbf[(t - tau) * kHBP + 4]);
            const float2* l2 = reinterpret_cast<const float2*>(&lo);
            const float2* h2 = reinterpret_cast<const float2*>(&hi);
            c01 = pkadd(c01, pkmul(l2[0], kv));
            c23 = pkadd(c23, pkmul(l2[1], kv));
            c45 = pkadd(c45, pkmul(h2[0], kv));
            c67 = pkadd(c67, pkmul(h2[1], kv));
        }
    }
    __syncthreads();                                  // all hbf reads complete

    cur[0 * kCURP + t] = (int)(c01.x * 64.0f);        // *64 exact, trunc
    cur[1 * kCURP + t] = (int)(c01.y * 64.0f);
    cur[2 * kCURP + t] = (int)(c23.x * 64.0f);
    cur[3 * kCURP + t] = (int)(c23.y * 64.0f);
    cur[4 * kCURP + t] = (int)(c45.x * 64.0f);
    cur[5 * kCURP + t] = (int)(c45.y * 64.0f);
    cur[6 * kCURP + t] = (int)(c67.x * 64.0f);
    cur[7 * kCURP + t] = (int)(c67.y * 64.0f);
    __syncthreads();

    // ---- serial int32 Loihi dynamics (lanes 0..7), PRE-DELAYED spikes ----
    if (t < kOT) {
        const int* cr = cur + t * kCURP;
        int u = 0, v = 0;
        sbuf[t * kSBP + 0] = 0;                       // delay_shift
        for (int s = 0; s < kT; ++s) {
            const int un = (int)((unsigned)decay_i(u, 3072) + (unsigned)cr[s]);
            int vn = (int)((unsigned)decay_i(v, 3968) + (unsigned)un);
            const int sp = (vn >= kTHETA) ? 1 : 0;
            if (sp) vn = 0;
            u = un; v = vn;
            if (s + 1 < kT) sbuf[t * kSBP + s + 1] = (unsigned char)sp;
        }
    }
    __syncthreads();

    // ---- pack 8 channel bits -> byte column SPT[b][oblk][t] ----
    unsigned byte = 0;
#pragma unroll
    for (int j = 0; j < kOT; ++j)
        byte |= (unsigned)sbuf[j * kSBP + t] << j;
    SPT[((size_t)b * 128 + oblk) * kT + t] = (unsigned char)byte;
}

// ============ k2: sparse GEMM over spike bytes + conv + scan + out ===========
__global__ __launch_bounds__(512) void k2_fused(const unsigned char* __restrict__ SPT,
                                                const float* __restrict__ W,
                                                float* __restrict__ O) {
    __shared__ float wlo[kHID * 4];                   // 16 KB
    __shared__ float whi[kHID * 4];                   // 16 KB
    __shared__ __align__(16) float hbf[kT * kHBP];    // 24 KB, aliased as cur
    __shared__ unsigned char sbuf[kOT * kSBP];
    __shared__ float kerf[kKMAX];
    __shared__ int   kn_s;

    int* cur = reinterpret_cast<int*>(hbf);

    const int t     = threadIdx.x;
    const int b     = blockIdx.x >> 5;                // 32 blocks per batch
    const int obase = (blockIdx.x & 31) * kOT;

    if (t == 0) kn_s = build_ker_f(kerf);
    for (int idx = t; idx < kOT * kHID; idx += 512) {
        const int j = idx >> 10, i = idx & 1023;
        const float w = W[(size_t)(obase + j) * kHID + i];
        if (j < 4) wlo[i * 4 + j] = w; else whi[i * 4 + (j - 4)] = w;
    }
    __syncthreads();

    // ---- assemble 32 mask words from 128 strided spike bytes, gather ----
    const unsigned char* sp = SPT + (size_t)b * (128 * kT) + t;
    float2 A01 = make_float2(0.f, 0.f), A23 = A01, A45 = A01, A67 = A01;
#define BW_(CB) ((unsigned)sp[(size_t)(CB) * kT])
#define MKW_(Wd) (BW_(4*(Wd)) | (BW_(4*(Wd)+1) << 8) | (BW_(4*(Wd)+2) << 16) | (BW_(4*(Wd)+3) << 24))
    {
        const unsigned w0=MKW_(0),  w1=MKW_(1),  w2=MKW_(2),  w3=MKW_(3),
                       w4=MKW_(4),  w5=MKW_(5),  w6=MKW_(6),  w7=MKW_(7),
                       w8=MKW_(8),  w9=MKW_(9),  wA=MKW_(10), wB=MKW_(11),
                       wC=MKW_(12), wD=MKW_(13), wE=MKW_(14), wF=MKW_(15);
        const unsigned g0=MKW_(16), g1=MKW_(17), g2=MKW_(18), g3=MKW_(19),
                       g4=MKW_(20), g5=MKW_(21), g6=MKW_(22), g7=MKW_(23),
                       g8=MKW_(24), g9=MKW_(25), gA=MKW_(26), gB=MKW_(27),
                       gC=MKW_(28), gD=MKW_(29), gE=MKW_(30), gF=MKW_(31);
        GWORD(w0,0)   GWORD(w1,32)  GWORD(w2,64)  GWORD(w3,96)
        GWORD(w4,128) GWORD(w5,160) GWORD(w6,192) GWORD(w7,224)
        GWORD(w8,256) GWORD(w9,288) GWORD(wA,320) GWORD(wB,352)
        GWORD(wC,384) GWORD(wD,416) GWORD(wE,448) GWORD(wF,480)
        GWORD(g0,512) GWORD(g1,544) GWORD(g2,576) GWORD(g3,608)
        GWORD(g4,640) GWORD(g5,672) GWORD(g6,704) GWORD(g7,736)
        GWORD(g8,768) GWORD(g9,800) GWORD(gA,832) GWORD(gB,864)
        GWORD(gC,896) GWORD(gD,928) GWORD(gE,960) GWORD(gF,992)
    }

    *reinterpret_cast<float2*>(&hbf[t * kHBP + 0]) = A01;
    *reinterpret_cast<float2*>(&hbf[t * kHBP + 2]) = A23;
    *reinterpret_cast<float2*>(&hbf[t * kHBP + 4]) = A45;
    *reinterpret_cast<float2*>(&hbf[t * kHBP + 6]) = A67;
    __syncthreads();

    float2 c01 = make_float2(0.f, 0.f), c23 = c01, c45 = c01, c67 = c01;
    {
        const int kmax = min(t + 1, kn_s);
        for (int tau = kmax - 1; tau >= 0; --tau) {
            const float kv = kerf[tau];
            const float4 lo = *reinterpret_cast<const float4*>(&hbf[(t - tau) * kHBP]);
            const float4 hi = *reinterpret_cast<const float4*>(&hbf[(t - tau) * kHBP + 4]);
            const float2* l2 = reinterpret_cast<const float2*>(&lo);
            const float2* h2 = reinterpret_cast<const float2*>(&hi);
            c01 = pkadd(c01, pkmul(l2[0], kv));
            c23 = pkadd(c23, pkmul(l2[1], kv));
            c45 = pkadd(c45, pkmul(h2[0], kv));
            c67 = pkadd(c67, pkmul(h2[1], kv));
        }
    }
    __syncthreads();

    cur[0 * kCURP + t] = (int)(c01.x * 64.0f);
    cur[1 * kCURP + t] = (int)(c01.y * 64.0f);
    cur[2 * kCURP + t] = (int)(c23.x * 64.0f);
    cur[3 * kCURP + t] = (int)(c23.y * 64.0f);
    cur[4 * kCURP + t] = (int)(c45.x * 64.0f);
    cur[5 * kCURP + t] = (int)(c45.y * 64.0f);
    cur[6 * kCURP + t] = (int)(c67.x * 64.0f);
    cur[7 * kCURP + t] = (int)(c67.y * 64.0f);
    __syncthreads();

    if (t < kOT) {
        const int* cr = cur + t * kCURP;
        int u = 0, v = 0;
        sbuf[t * kSBP + 0] = 0;                       // delay_shift on output
        for (int s = 0; s < kT; ++s) {
            const int un = (int)((unsigned)decay_i(u, 3072) + (unsigned)cr[s]);
            int vn = (int)((unsigned)decay_i(v, 3968) + (unsigned)un);
            const int sp2 = (vn >= kTHETA) ? 1 : 0;
            if (sp2) vn = 0;
            u = un; v = vn;
            if (s + 1 < kT) sbuf[t * kSBP + s + 1] = (unsigned char)sp2;
        }
    }
    __syncthreads();

    for (int idx = t; idx < kOT * kT; idx += 512) {
        const int j = idx >> 9, tt = idx & 511;
        O[((size_t)(b * kCOUT + obase + j)) * kT + tt] = (float)sbuf[j * kSBP + tt];
    }
}

__global__ void k_mark(float* __restrict__ out0, float v) {
    if (threadIdx.x == 0 && blockIdx.x == 0) out0[0] = v;
}

extern "C" void kernel_launch(void* const* d_in, const int* in_sizes, int n_in,
                              void* d_out, int out_size, void* d_ws, size_t ws_size,
                              hipStream_t stream) {
    const float* X  = (const float*)d_in[0];   // (32,512,1,1,512) spikes {0,1}
    const float* W1 = (const float*)d_in[1];   // (1024,512)
    const float* W2 = (const float*)d_in[2];   // (256,1024)
    float* OUT = (float*)d_out;                // (32,256,1,1,512)

    const size_t xpw_bytes = (size_t)kB * 16 * kT * 4;      // 1 MiB
    const size_t spt_bytes = (size_t)kB * 128 * kT;         // 2 MiB
    const size_t need = xpw_bytes + spt_bytes;

    if (n_in != 3 || in_sizes[0] != kB * kCIN * kT || in_sizes[1] != kHID * kCIN ||
        in_sizes[2] != kCOUT * kHID || out_size != kB * kCOUT * kT) {
        hipLaunchKernelGGL(k_mark, dim3(1), dim3(64), 0, stream, OUT, 7000001.0f);
        return;
    }
    if (ws_size < need || d_ws == nullptr) {
        const float v = (float)(8000000u + (unsigned)((ws_size >> 10) % 900000));
        hipLaunchKernelGGL(k_mark, dim3(1), dim3(64), 0, stream, OUT, v);
        return;
    }

    unsigned*      xpw = (unsigned*)d_ws;
    unsigned char* spt = (unsigned char*)d_ws + xpw_bytes;

    hipLaunchKernelGGL(k0_pack, dim3(kB * 16 * kT / 256), dim3(256), 0, stream,
                       X, xpw);
    hipLaunchKernelGGL(k1_fused, dim3(kB * (kHID / kOT)), dim3(512), 0, stream,
                       xpw, W1, spt);
    hipLaunchKernelGGL(k2_fused, dim3(kB * (kCOUT / kOT)), dim3(512), 0, stream,
                       spt, W2, OUT);
}

// Round 9
// 614.760 us; speedup vs baseline: 1.5079x; 1.1289x over previous
//
#include <hip/hip_runtime.h>

// SlayerLoihiMLP: bit-exact f32 replication of the numpy reference (verified
// r5/r6/r7/r8, absmax 0.0). Round 9: r8 pipeline + 2-col conv (r7's proven
// float4 = 2cols x 2ch layout, now with ALL 512 threads active) + LDS region
// aliasing (W/h/cur share one region, phase barriers) -> 4 blocks/CU.
// Exactness invariants:
//  - GEMM: per-output ordered ascending-i f32 sum; skipping x==0 terms is
//    bit-exact (RNE running sums never produce -0.0; +0.0 adds are identity).
//  - conv: f32 mul then add (contract OFF file-wide), taps tau-descending per
//    output col (87..0, incl. the exact-zero tap 87); taps = (64*SRM)/64 exact;
//    *64.0f (exact) then trunc-to-int32.
//  - neuron dynamics: bit-exact int32 with jnp wrap semantics.
//  - float2 packing pairs INDEPENDENT channel accumulators.

#pragma clang fp contract(off)

constexpr int kT     = 512;
constexpr int kCIN   = 512;
constexpr int kHID   = 1024;
constexpr int kCOUT  = 256;
constexpr int kB     = 32;
constexpr int kTHETA = 5120;   // 80 << 6
constexpr int kOT    = 8;      // output channels per block
constexpr int kSBP   = 516;    // sbuf row pitch (bytes)
constexpr int kCURP  = 520;    // cur row pitch (ints)

// ---- SRM kernel taps at compile time: v[tau] = (64*SRM_KERNEL[tau])/64 ----
struct Ker { float v[96]; int n; };
constexpr Ker mk_ker() {
    Ker K{}; int u = 64, v = 64; K.v[0] = 1.0f; int i = 1;
    while (v > 0 && i < 96) {
        u = (u * 3072) >> 12;
        v = ((v * 3968) >> 12) + u;
        K.v[i++] = (float)v / 64.0f;   // exact (v <= 194)
    }
    K.n = i; return K;
}
constexpr Ker KER = mk_ker();
static_assert(KER.n == 88, "SRM kernel length must be 88");
static_assert(KER.v[87] == 0.0f, "tap 87 must be the exact zero tail tap");

__device__ __forceinline__ float2 pkmul(const float2 a, const float b) {
    return make_float2(a.x * b, a.y * b);
}
__device__ __forceinline__ float2 pkadd(const float2 a, const float2 b) {
    return make_float2(a.x + b.x, a.y + b.y);
}

__device__ __forceinline__ int decay_i(int x, int mult) {
    unsigned ax = (x >= 0) ? (unsigned)x : (0u - (unsigned)x);
    unsigned p  = ax * (unsigned)mult;   // int32 wrap like jnp
    int sh = ((int)p) >> 12;             // arithmetic shift like jnp int32 >>
    return (x >= 0) ? sh : (int)(0u - (unsigned)sh);
}

// sparse gather of one 32-bit mask word into 4 float2 accumulators
#define GWORD(MW, BASE) { unsigned m_ = (MW); while (m_) { \
    const int bi_ = __ffs(m_) - 1; m_ &= m_ - 1; const int ii_ = (BASE) + bi_; \
    const float4 lo = *reinterpret_cast<const float4*>(&wlo[ii_ * 4]); \
    const float4 hi = *reinterpret_cast<const float4*>(&whi[ii_ * 4]); \
    A01 = pkadd(A01, make_float2(lo.x, lo.y)); \
    A23 = pkadd(A23, make_float2(lo.z, lo.w)); \
    A45 = pkadd(A45, make_float2(hi.x, hi.y)); \
    A67 = pkadd(A67, make_float2(hi.z, hi.w)); } }

// ---- conv: 2 cols/thread, h as float4 = (col even, col odd) x (2 ch) ----
// thread: p = col pair (0..255), half = ch half (0..1 -> ch 4h..4h+3).
#define LOADP(RP) \
    const float4 g0 = hq[(2 * half + 0) * 256 + (RP)]; \
    const float4 g1 = hq[(2 * half + 1) * 256 + (RP)];
#define ACC_ES(C01, C23, KV) \
    C01 = pkadd(C01, pkmul(make_float2(g0.x, g0.y), (KV))); \
    C23 = pkadd(C23, pkmul(make_float2(g1.x, g1.y), (KV)));
#define ACC_OS(C01, C23, KV) \
    C01 = pkadd(C01, pkmul(make_float2(g0.z, g0.w), (KV))); \
    C23 = pkadd(C23, pkmul(make_float2(g1.z, g1.w), (KV)));

// taps per output col strictly descending 87..0 (verified per-tap):
//  colE=2p: 87(odd rp p-44), then s=43..1: 2s(even rp p-s), 2s-1(odd rp p-s),
//           then 0(even rp p).
//  colO=2p+1: s=43..1: 2s+1(even rp p-s), 2s(odd rp p-s), then 1(even rp p),
//           0(odd rp p).
#define CONV_BODY() \
    if (p >= 44) { \
        { LOADP(p - 44) ACC_OS(cE01, cE23, KER.v[87]) } \
        _Pragma("unroll") \
        for (int s = 43; s >= 1; --s) { \
            LOADP(p - s) \
            ACC_ES(cO01, cO23, KER.v[2 * s + 1]) \
            ACC_ES(cE01, cE23, KER.v[2 * s]) \
            ACC_OS(cO01, cO23, KER.v[2 * s]) \
            ACC_OS(cE01, cE23, KER.v[2 * s - 1]) \
        } \
        { LOADP(p) \
          ACC_ES(cO01, cO23, KER.v[1]) \
          ACC_ES(cE01, cE23, KER.v[0]) \
          ACC_OS(cO01, cO23, KER.v[0]) } \
    } else { \
        const int tc0 = 2 * p, tc1 = 2 * p + 1; \
        for (int tau = tc0; tau >= 0; --tau) { \
            const int r = tc0 - tau; const int rp = r >> 1; const int od = r & 1; \
            LOADP(rp) const float kv = KER.v[tau]; \
            const float2 s0 = od ? make_float2(g0.z, g0.w) : make_float2(g0.x, g0.y); \
            const float2 s1 = od ? make_float2(g1.z, g1.w) : make_float2(g1.x, g1.y); \
            cE01 = pkadd(cE01, pkmul(s0, kv)); \
            cE23 = pkadd(cE23, pkmul(s1, kv)); \
        } \
        for (int tau = tc1; tau >= 0; --tau) { \
            const int r = tc1 - tau; const int rp = r >> 1; const int od = r & 1; \
            LOADP(rp) const float kv = KER.v[tau]; \
            const float2 s0 = od ? make_float2(g0.z, g0.w) : make_float2(g0.x, g0.y); \
            const float2 s1 = od ? make_float2(g1.z, g1.w) : make_float2(g1.x, g1.y); \
            cO01 = pkadd(cO01, pkmul(s0, kv)); \
            cO23 = pkadd(cO23, pkmul(s1, kv)); \
        } \
    }

// h staging (gather thread t owns col t, 8 ch in A01..A67)
#define H_STORE() { \
    const int rp = t >> 1, od = t & 1; \
    hb2[(((0 * 256 + rp) << 1) | od)] = A01; \
    hb2[(((1 * 256 + rp) << 1) | od)] = A23; \
    hb2[(((2 * 256 + rp) << 1) | od)] = A45; \
    hb2[(((3 * 256 + rp) << 1) | od)] = A67; }

// cur staging from conv accumulators (*64 exact, trunc toward 0)
#define CUR_STORE() { \
    int2* cur2 = reinterpret_cast<int2*>(cur); \
    cur2[(4 * half + 0) * 260 + p] = make_int2((int)(cE01.x * 64.0f), (int)(cO01.x * 64.0f)); \
    cur2[(4 * half + 1) * 260 + p] = make_int2((int)(cE01.y * 64.0f), (int)(cO01.y * 64.0f)); \
    cur2[(4 * half + 2) * 260 + p] = make_int2((int)(cE23.x * 64.0f), (int)(cO23.x * 64.0f)); \
    cur2[(4 * half + 3) * 260 + p] = make_int2((int)(cE23.y * 64.0f), (int)(cO23.y * 64.0f)); }

// serial int32 Loihi dynamics, lanes 0..7, PRE-DELAYED spikes into sbuf
#define SCAN_BODY() \
    if (t < kOT) { \
        const int* cr = cur + t * kCURP; \
        int u = 0, v = 0; \
        sbuf[t * kSBP + 0] = 0; \
        for (int s = 0; s < kT; ++s) { \
            const int un = (int)((unsigned)decay_i(u, 3072) + (unsigned)cr[s]); \
            int vn = (int)((unsigned)decay_i(v, 3968) + (unsigned)un); \
            const int sp_ = (vn >= kTHETA) ? 1 : 0; \
            if (sp_) vn = 0; \
            u = un; v = vn; \
            if (s + 1 < kT) sbuf[t * kSBP + s + 1] = (unsigned char)sp_; \
        } \
    }

// =============== k0: pack X into bit masks XPW[b][w=i/32][t] =================
__global__ __launch_bounds__(256) void k0_pack(const float* __restrict__ X,
                                               unsigned* __restrict__ XPW) {
    const int tid = blockIdx.x * 256 + threadIdx.x;   // [b][w][t] flat
    const int b = tid >> 13, rem = tid & 8191, w = rem >> 9, t = rem & 511;
    const float* xp = X + ((size_t)(b * kCIN + w * 32)) * kT + t;
    unsigned m = 0;
#pragma unroll
    for (int k = 0; k < 32; ++k)
        m |= (xp[(size_t)k * kT] != 0.0f ? 1u : 0u) << k;
    XPW[tid] = m;
}

// ============ k1: sparse GEMM (masks) + 2-col conv + scan, fused =============
__global__ __launch_bounds__(512) void k1_fused(const unsigned* __restrict__ XPW,
                                                const float* __restrict__ W,
                                                unsigned char* __restrict__ SPT) {
    // one aliased region: W (16KB) -> h (16KB) -> cur (16640B), phase barriers
    __shared__ __align__(16) unsigned char regn[16640];
    __shared__ unsigned char sbuf[kOT * kSBP];

    float*  wlo = reinterpret_cast<float*>(regn);            // [512][4] ch0-3
    float*  whi = reinterpret_cast<float*>(regn + 8192);     // [512][4] ch4-7
    float4* hq  = reinterpret_cast<float4*>(regn);           // [4][256] f4
    float2* hb2 = reinterpret_cast<float2*>(regn);
    int*    cur = reinterpret_cast<int*>(regn);              // [8][520] ints

    const int t     = threadIdx.x;
    const int b     = blockIdx.x >> 7;               // 128 blocks per batch
    const int oblk  = blockIdx.x & 127;
    const int obase = oblk * kOT;

    for (int idx = t; idx < kOT * kCIN; idx += 512) {
        const int j = idx >> 9, i = idx & 511;
        const float w = W[(size_t)(obase + j) * kCIN + i];
        if (j < 4) wlo[i * 4 + j] = w; else whi[i * 4 + (j - 4)] = w;
    }
    __syncthreads();

    // ---- sparse GEMM: ordered ascending-i adds of W columns where x==1 ----
    const unsigned* xw = XPW + ((size_t)b * 16) * kT + t;
    float2 A01 = make_float2(0.f, 0.f), A23 = A01, A45 = A01, A67 = A01;
    {
        const unsigned m0=xw[0],    m1=xw[512],  m2=xw[1024], m3=xw[1536],
                       m4=xw[2048], m5=xw[2560], m6=xw[3072], m7=xw[3584],
                       m8=xw[4096], m9=xw[4608], mA=xw[5120], mB=xw[5632],
                       mC=xw[6144], mD=xw[6656], mE=xw[7168], mF=xw[7680];
        GWORD(m0,0)   GWORD(m1,32)  GWORD(m2,64)  GWORD(m3,96)
        GWORD(m4,128) GWORD(m5,160) GWORD(m6,192) GWORD(m7,224)
        GWORD(m8,256) GWORD(m9,288) GWORD(mA,320) GWORD(mB,352)
        GWORD(mC,384) GWORD(mD,416) GWORD(mE,448) GWORD(mF,480)
    }
    __syncthreads();   // all W reads complete (h overwrites W region)

    H_STORE();
    __syncthreads();

    const int p = t & 255, half = t >> 8;
    float2 cE01 = make_float2(0.f, 0.f), cE23 = cE01, cO01 = cE01, cO23 = cE01;
    CONV_BODY();
    __syncthreads();   // all h reads complete (cur overwrites h region)

    CUR_STORE();
    __syncthreads();

    SCAN_BODY();
    __syncthreads();

    // ---- pack 8 channel bits -> byte column SPT[b][oblk][t] ----
    unsigned byte = 0;
#pragma unroll
    for (int j = 0; j < kOT; ++j)
        byte |= (unsigned)sbuf[j * kSBP + t] << j;
    SPT[((size_t)b * 128 + oblk) * kT + t] = (unsigned char)byte;
}

// ============ k2: sparse GEMM over spike bytes + 2-col conv + scan + out =====
__global__ __launch_bounds__(512) void k2_fused(const unsigned char* __restrict__ SPT,
                                                const float* __restrict__ W,
                                                float* __restrict__ O) {
    // region: W (32KB) -> h (16KB) + cur (16640B), phase barriers
    __shared__ __align__(16) unsigned char regn[33280];
    __shared__ unsigned char sbuf[kOT * kSBP];

    float*  wlo = reinterpret_cast<float*>(regn);             // [1024][4] ch0-3
    float*  whi = reinterpret_cast<float*>(regn + 16384);     // [1024][4] ch4-7
    float4* hq  = reinterpret_cast<float4*>(regn);            // [4][256] f4
    float2* hb2 = reinterpret_cast<float2*>(regn);
    int*    cur = reinterpret_cast<int*>(regn + 16384);       // disjoint from h

    const int t     = threadIdx.x;
    const int b     = blockIdx.x >> 5;               // 32 blocks per batch
    const int obase = (blockIdx.x & 31) * kOT;

    for (int idx = t; idx < kOT * kHID; idx += 512) {
        const int j = idx >> 10, i = idx & 1023;
        const float w = W[(size_t)(obase + j) * kHID + i];
        if (j < 4) wlo[i * 4 + j] = w; else whi[i * 4 + (j - 4)] = w;
    }
    __syncthreads();

    // ---- assemble mask words from strided spike bytes, ordered gather ----
    const unsigned char* sp = SPT + (size_t)b * (128 * kT) + t;
    float2 A01 = make_float2(0.f, 0.f), A23 = A01, A45 = A01, A67 = A01;
    for (int wd = 0; wd < 32; ++wd) {
        const unsigned b0 = sp[(size_t)(4 * wd + 0) * kT];
        const unsigned b1 = sp[(size_t)(4 * wd + 1) * kT];
        const unsigned b2 = sp[(size_t)(4 * wd + 2) * kT];
        const unsigned b3 = sp[(size_t)(4 * wd + 3) * kT];
        const unsigned m = b0 | (b1 << 8) | (b2 << 16) | (b3 << 24);
        GWORD(m, wd * 32)
    }
    __syncthreads();   // all W reads complete

    H_STORE();
    __syncthreads();

    const int p = t & 255, half = t >> 8;
    float2 cE01 = make_float2(0.f, 0.f), cE23 = cE01, cO01 = cE01, cO23 = cE01;
    CONV_BODY();
    __syncthreads();

    CUR_STORE();
    __syncthreads();

    SCAN_BODY();
    __syncthreads();

    for (int idx = t; idx < kOT * kT; idx += 512) {
        const int j = idx >> 9, tt = idx & 511;
        O[((size_t)(b * kCOUT + obase + j)) * kT + tt] = (float)sbuf[j * kSBP + tt];
    }
}

__global__ void k_mark(float* __restrict__ out0, float v) {
    if (threadIdx.x == 0 && blockIdx.x == 0) out0[0] = v;
}

extern "C" void kernel_launch(void* const* d_in, const int* in_sizes, int n_in,
                              void* d_out, int out_size, void* d_ws, size_t ws_size,
                              hipStream_t stream) {
    const float* X  = (const float*)d_in[0];   // (32,512,1,1,512) spikes {0,1}
    const float* W1 = (const float*)d_in[1];   // (1024,512)
    const float* W2 = (const float*)d_in[2];   // (256,1024)
    float* OUT = (float*)d_out;                // (32,256,1,1,512)

    const size_t xpw_bytes = (size_t)kB * 16 * kT * 4;      // 1 MiB
    const size_t spt_bytes = (size_t)kB * 128 * kT;         // 2 MiB
    const size_t need = xpw_bytes + spt_bytes;

    if (n_in != 3 || in_sizes[0] != kB * kCIN * kT || in_sizes[1] != kHID * kCIN ||
        in_sizes[2] != kCOUT * kHID || out_size != kB * kCOUT * kT) {
        hipLaunchKernelGGL(k_mark, dim3(1), dim3(64), 0, stream, OUT, 7000001.0f);
        return;
    }
    if (ws_size < need || d_ws == nullptr) {
        const float v = (float)(8000000u + (unsigned)((ws_size >> 10) % 900000));
        hipLaunchKernelGGL(k_mark, dim3(1), dim3(64), 0, stream, OUT, v);
        return;
    }

    unsigned*      xpw = (unsigned*)d_ws;
    unsigned char* spt = (unsigned char*)d_ws + xpw_bytes;

    hipLaunchKernelGGL(k0_pack, dim3(kB * 16 * kT / 256), dim3(256), 0, stream,
                       X, xpw);
    hipLaunchKernelGGL(k1_fused, dim3(kB * (kHID / kOT)), dim3(512), 0, stream,
                       xpw, W1, spt);
    hipLaunchKernelGGL(k2_fused, dim3(kB * (kCOUT / kOT)), dim3(512), 0, stream,
                       spt, W2, OUT);
}